// Round 1
// baseline (2354.054 us; speedup 1.0000x reference)
//
#include <hip/hip_runtime.h>
#include <math.h>

#define EMBS 32
#define INS 64
#define HS 128
#define OUTS 256
#define BS 64
#define SS 2048

typedef _Float16 half2v __attribute__((ext_vector_type(2)));

// ws layout (floats): emb [B][S][IN] | dist [B][IN] | hfin [B][H]
static constexpr size_t WS_DIST  = (size_t)BS * SS * INS;
static constexpr size_t WS_HFIN  = WS_DIST + (size_t)BS * INS;
static constexpr size_t WS_TOTAL = WS_HFIN + (size_t)BS * HS;

__device__ __forceinline__ float sigm(float x) { return 1.f / (1.f + expf(-x)); }

__device__ __forceinline__ float fdot2f(half2v a, half2v b, float c) {
#if __has_builtin(__builtin_amdgcn_fdot2)
    return __builtin_amdgcn_fdot2(a, b, c, false);
#else
    return c + (float)a.x * (float)b.x + (float)a.y * (float)b.y;
#endif
}

__device__ __forceinline__ half2v pack2(float a, float b) {
    half2v r; r.x = (_Float16)a; r.y = (_Float16)b; return r;
}

// ---------------------------------------------------------------------------
// K1: byte-decompose + embedding gather + encoder MLP (both pc and addr)
// one thread per (b, t). Encoder weights are wave-uniform -> scalar loads.
// ---------------------------------------------------------------------------
__global__ __launch_bounds__(256) void k_embed(
    const int* __restrict__ inp, const float* __restrict__ pc_emb,
    const float* __restrict__ ad_emb, const float* __restrict__ encW,
    const float* __restrict__ encB, float* __restrict__ emb)
{
    int idx = blockIdx.x * 256 + threadIdx.x;   // 512 blocks * 256 = B*S exactly
    int b = idx >> 11, t = idx & 2047;
    size_t base = (size_t)b * SS + t;
    int2 pa = ((const int2*)inp)[base];
    float* outp = emb + base * INS;

    float in[128];
    #pragma unroll
    for (int st = 0; st < 2; st++) {
        int v = (st == 0) ? pa.x : pa.y;
        const float* tbl = (st == 0) ? pc_emb : ad_emb;
        #pragma unroll
        for (int i = 0; i < 4; i++) {
            int by = (v >> (24 - 8 * i)) & 255;
            const float4* row = (const float4*)(tbl + ((size_t)i * 256 + by) * EMBS);
            #pragma unroll
            for (int k = 0; k < 8; k++) {
                float4 f = row[k];
                in[i * 32 + k * 4 + 0] = f.x;
                in[i * 32 + k * 4 + 1] = f.y;
                in[i * 32 + k * 4 + 2] = f.z;
                in[i * 32 + k * 4 + 3] = f.w;
            }
        }
        for (int e = 0; e < EMBS; e++) {        // e uniform -> encW via s_load
            const float* w = encW + e * 128;
            float acc = encB[e];
            #pragma unroll
            for (int k = 0; k < 128; k++) acc += in[k] * w[k];
            outp[st * EMBS + e] = sigm(acc);
        }
    }
}

// ---------------------------------------------------------------------------
// K2: dist[b][j] = mean over t of emb[b][t][j]
// ---------------------------------------------------------------------------
__global__ __launch_bounds__(256) void k_dist(const float* __restrict__ emb,
                                              float* __restrict__ dist)
{
    int b = blockIdx.x;
    int j = threadIdx.x & 63;
    int grp = threadIdx.x >> 6;
    float s = 0.f;
    for (int t = grp; t < SS; t += 4) s += emb[((size_t)b * SS + t) * INS + j];
    __shared__ float red[4][64];
    red[grp][j] = s;
    __syncthreads();
    if (grp == 0)
        dist[b * 64 + j] = (red[0][j] + red[1][j] + red[2][j] + red[3][j]) * (1.f / SS);
}

// ---------------------------------------------------------------------------
// K3: LSTM, one block per batch element. f16 weights in VGPRs, dot2 accum fp32.
// thread tid handles gates (tid, tid+256):
//   tid <128: (i_u, g_u) for u=tid   | tid>=128: (f_u, o_u) for u=tid-128
// ---------------------------------------------------------------------------
__global__ __launch_bounds__(256, 1) void k_lstm(
    const float* __restrict__ emb, const float* __restrict__ h0,
    const float* __restrict__ c0, const float* __restrict__ Wih,
    const float* __restrict__ Whh, const float* __restrict__ bih,
    const float* __restrict__ bhh, float* __restrict__ hfin)
{
    int b = blockIdx.x;
    int tid = threadIdx.x;

    // preload weights (2 gates/thread) as packed f16
    half2v wih[2][32], whh[2][64];
    #pragma unroll
    for (int g = 0; g < 2; g++) {
        int gg = tid + g * 256;
        const float* wr = Wih + (size_t)gg * INS;
        #pragma unroll
        for (int i = 0; i < 32; i++) wih[g][i] = pack2(wr[2 * i], wr[2 * i + 1]);
        const float* hr = Whh + (size_t)gg * HS;
        #pragma unroll
        for (int i = 0; i < 64; i++) whh[g][i] = pack2(hr[2 * i], hr[2 * i + 1]);
    }
    float bias0 = bih[tid] + bhh[tid];
    float bias1 = bih[tid + 256] + bhh[tid + 256];

    __shared__ alignas(16) half2v xh[96];   // [0:32] x pairs, [32:96] h pairs
    __shared__ float f_act[128], o_act[128];
    __shared__ float xf[64], hf[128];

    float c = 0.f, h = 0.f;
    if (tid < 128) c = c0[b * HS + tid];

    const float* xrow = emb + (size_t)b * SS * INS;
    if (tid < 64) xf[tid] = xrow[tid];
    if (tid < 128) hf[tid] = h0[b * HS + tid];
    __syncthreads();
    if (tid < 32) xh[tid] = pack2(xf[2 * tid], xf[2 * tid + 1]);
    else if (tid < 96) { int u = tid - 32; xh[tid] = pack2(hf[2 * u], hf[2 * u + 1]); }
    __syncthreads();

    for (int t = 0; t < SS; t++) {
        // prefetch next x (wave 2), latency hidden under the dot loop
        float xn = 0.f;
        if (tid >= 128 && tid < 192 && t + 1 < SS) xn = xrow[(size_t)(t + 1) * INS + (tid - 128)];

        // gate pre-activations: 2 gates, 4 accumulation chains for ILP
        float a0a = 0.f, a0b = 0.f, a1a = 0.f, a1b = 0.f;
        #pragma unroll
        for (int i = 0; i < 32; i += 2) {
            half2v x0 = xh[i], x1 = xh[i + 1];
            a0a = fdot2f(x0, wih[0][i], a0a);
            a0b = fdot2f(x1, wih[0][i + 1], a0b);
            a1a = fdot2f(x0, wih[1][i], a1a);
            a1b = fdot2f(x1, wih[1][i + 1], a1b);
        }
        #pragma unroll
        for (int i = 0; i < 64; i += 2) {
            half2v h0v = xh[32 + i], h1v = xh[32 + i + 1];
            a0a = fdot2f(h0v, whh[0][i], a0a);
            a0b = fdot2f(h1v, whh[0][i + 1], a0b);
            a1a = fdot2f(h0v, whh[1][i], a1a);
            a1b = fdot2f(h1v, whh[1][i + 1], a1b);
        }
        float a0 = bias0 + a0a + a0b;
        float a1 = bias1 + a1a + a1b;

        float iact = 0.f, gact = 0.f;
        if (tid < 128) { iact = sigm(a0); gact = tanhf(a1); }
        else           { f_act[tid - 128] = sigm(a0); o_act[tid - 128] = sigm(a1); }
        __syncthreads();

        if (tid < 128) {
            c = f_act[tid] * c + iact * gact;
            h = o_act[tid] * tanhf(c);
            hf[tid] = h;
        } else if (tid < 192) {
            xf[tid - 128] = xn;
        }
        __syncthreads();

        if (tid < 32) xh[tid] = pack2(xf[2 * tid], xf[2 * tid + 1]);
        else if (tid < 96) { int u = tid - 32; xh[tid] = pack2(hf[2 * u], hf[2 * u + 1]); }
        __syncthreads();
    }
    if (tid < 128) hfin[b * HS + tid] = h;
}

// ---------------------------------------------------------------------------
// K4: decoder logits + T=1e-3 softmax + freq-rec head. one block per b.
// ---------------------------------------------------------------------------
__global__ __launch_bounds__(256) void k_head(
    const float* __restrict__ hfin, const float* __restrict__ decW,
    const float* __restrict__ decB, const float* __restrict__ ad_emb,
    const float* __restrict__ encW, const float* __restrict__ encB,
    const float* __restrict__ dist, const float* __restrict__ fc1W,
    const float* __restrict__ fc1b, const float* __restrict__ fc2W,
    const float* __restrict__ fc2b, float* __restrict__ outp)
{
    int b = blockIdx.x;
    int tid = threadIdx.x;      // tid == o for the logit phase
    __shared__ float hsh[128];
    __shared__ float logit_s[4][256];
    __shared__ float probs_s[4][256];
    __shared__ float be_s[128];
    __shared__ float fe_dist[96];
    __shared__ float fr1[10];

    if (tid < 128) hsh[tid] = hfin[b * HS + tid];
    __syncthreads();

    #pragma unroll
    for (int k = 0; k < 4; k++) {
        const float* w = decW + ((size_t)k * OUTS + tid) * HS;
        float acc = decB[k * OUTS + tid];
        #pragma unroll 8
        for (int hh = 0; hh < HS; hh++) acc += hsh[hh] * w[hh];
        logit_s[k][tid] = acc;
        outp[65536 + k * 16384 + b * 256 + tid] = acc;   // logits output
    }
    __syncthreads();

    // one wave per k: softmax over 256 entries
    {
        int k = tid >> 6, lane = tid & 63;
        float v0 = logit_s[k][lane],       v1 = logit_s[k][lane + 64];
        float v2 = logit_s[k][lane + 128], v3 = logit_s[k][lane + 192];
        float m = fmaxf(fmaxf(v0, v1), fmaxf(v2, v3));
        for (int off = 32; off; off >>= 1) m = fmaxf(m, __shfl_xor(m, off, 64));
        float e0 = expf((v0 - m) * 1000.f), e1 = expf((v1 - m) * 1000.f);
        float e2 = expf((v2 - m) * 1000.f), e3 = expf((v3 - m) * 1000.f);
        float s = e0 + e1 + e2 + e3;
        for (int off = 32; off; off >>= 1) s += __shfl_xor(s, off, 64);
        float inv = 1.f / s;
        float p0 = e0 * inv, p1 = e1 * inv, p2 = e2 * inv, p3 = e3 * inv;
        probs_s[k][lane] = p0;        probs_s[k][lane + 64] = p1;
        probs_s[k][lane + 128] = p2;  probs_s[k][lane + 192] = p3;
        outp[k * 16384 + b * 256 + lane] = p0;
        outp[k * 16384 + b * 256 + lane + 64] = p1;
        outp[k * 16384 + b * 256 + lane + 128] = p2;
        outp[k * 16384 + b * 256 + lane + 192] = p3;
    }
    __syncthreads();

    // be[k][e] = sum_o probs[k][o] * addr_emb[k][o][e]
    if (tid < 128) {
        int k = tid >> 5, e = tid & 31;
        const float* te = ad_emb + (size_t)k * OUTS * EMBS + e;
        float acc = 0.f;
        #pragma unroll 8
        for (int o = 0; o < OUTS; o++) acc += probs_s[k][o] * te[o * EMBS];
        be_s[tid] = acc;
    }
    __syncthreads();

    if (tid < 32) {
        const float* w = encW + tid * 128;
        float acc = encB[tid];
        #pragma unroll 8
        for (int kk = 0; kk < 128; kk++) acc += be_s[kk] * w[kk];
        fe_dist[tid] = sigm(acc);
    } else if (tid < 96) {
        fe_dist[tid] = dist[b * 64 + (tid - 32)];
    }
    __syncthreads();

    if (tid < 10) {
        float acc = fc1b[tid];
        for (int kk = 0; kk < 96; kk++) acc += fe_dist[kk] * fc1W[tid * 96 + kk];
        fr1[tid] = fmaxf(acc, 0.f);
    }
    __syncthreads();

    if (tid < 2) {
        float acc = fc2b[tid];
        for (int kk = 0; kk < 10; kk++) acc += fr1[kk] * fc2W[tid * 10 + kk];
        outp[131072 + tid * 64 + b] = sigm(acc);
    }
}

// ---------------------------------------------------------------------------
extern "C" void kernel_launch(void* const* d_in, const int* in_sizes, int n_in,
                              void* d_out, int out_size, void* d_ws, size_t ws_size,
                              hipStream_t stream)
{
    const int*   inp    = (const int*)d_in[0];
    const float* h0     = (const float*)d_in[1];
    const float* c0     = (const float*)d_in[2];
    const float* pc_emb = (const float*)d_in[3];
    const float* ad_emb = (const float*)d_in[4];
    const float* encW   = (const float*)d_in[5];
    const float* encB   = (const float*)d_in[6];
    const float* Wih    = (const float*)d_in[7];
    const float* Whh    = (const float*)d_in[8];
    const float* bih    = (const float*)d_in[9];
    const float* bhh    = (const float*)d_in[10];
    const float* decW   = (const float*)d_in[11];
    const float* decB   = (const float*)d_in[12];
    const float* fc1W   = (const float*)d_in[13];
    const float* fc1b   = (const float*)d_in[14];
    const float* fc2W   = (const float*)d_in[15];
    const float* fc2b   = (const float*)d_in[16];

    if (ws_size < WS_TOTAL * sizeof(float)) return;  // clean fail if ws too small

    float* ws   = (float*)d_ws;
    float* emb  = ws;
    float* dist = ws + WS_DIST;
    float* hfin = ws + WS_HFIN;
    float* outp = (float*)d_out;

    hipLaunchKernelGGL(k_embed, dim3(512), dim3(256), 0, stream,
                       inp, pc_emb, ad_emb, encW, encB, emb);
    hipLaunchKernelGGL(k_dist, dim3(64), dim3(256), 0, stream, emb, dist);
    hipLaunchKernelGGL(k_lstm, dim3(64), dim3(256), 0, stream,
                       emb, h0, c0, Wih, Whh, bih, bhh, hfin);
    hipLaunchKernelGGL(k_head, dim3(64), dim3(256), 0, stream,
                       hfin, decW, decB, ad_emb, encW, encB, dist,
                       fc1W, fc1b, fc2W, fc2b, outp);
}

// Round 2
// 1579.526 us; speedup vs baseline: 1.4904x; 1.4904x over previous
//
#include <hip/hip_runtime.h>
#include <math.h>
#include <stdint.h>

#define EMBS 32
#define INS 64
#define HS 128
#define OUTS 256
#define BS 64
#define SS 2048

typedef _Float16 half2v __attribute__((ext_vector_type(2)));

// ws layout (4B elems): emb [B][S][IN] f32 | dist [B][IN] f32 | hfin [B][H] f32 | xw [B][S][256] u32(2xf16)
static constexpr size_t WS_DIST  = (size_t)BS * SS * INS;
static constexpr size_t WS_HFIN  = WS_DIST + (size_t)BS * INS;
static constexpr size_t WS_XW    = WS_HFIN + (size_t)BS * HS;
static constexpr size_t WS_SMALL = WS_XW;                       // elems without xw
static constexpr size_t WS_BIG   = WS_XW + (size_t)BS * SS * 256; // elems with xw

__device__ __forceinline__ float fexp2(float x) {
#if __has_builtin(__builtin_amdgcn_exp2f)
    return __builtin_amdgcn_exp2f(x);
#else
    return exp2f(x);
#endif
}
__device__ __forceinline__ float frcp(float x) {
#if __has_builtin(__builtin_amdgcn_rcpf)
    return __builtin_amdgcn_rcpf(x);
#else
    return 1.f / x;
#endif
}
// sigmoid / tanh via v_exp_f32 (2^x) + v_rcp_f32; saturate correctly at +-inf
__device__ __forceinline__ float sigm(float x)  { return frcp(1.f + fexp2(-1.44269504f * x)); }
__device__ __forceinline__ float ftanh(float x) { return 1.f - 2.f * frcp(1.f + fexp2(2.88539008f * x)); }

__device__ __forceinline__ float fdot2f(half2v a, half2v b, float c) {
#if __has_builtin(__builtin_amdgcn_fdot2)
    return __builtin_amdgcn_fdot2(a, b, c, false);
#else
    return c + (float)a.x * (float)b.x + (float)a.y * (float)b.y;
#endif
}

__device__ __forceinline__ half2v pack2(float a, float b) {
    half2v r; r.x = (_Float16)a; r.y = (_Float16)b; return r;
}

// gate-row mapping shared by k_xw and k_lstm2:
// wave w lanes 0-31 own units u=32w+l with gate pair (i_u, g_u) = rows (u, 256+u)
// wave w lanes 32-63 own same units with pair (f_u, o_u) = rows (128+u, 384+u)
__device__ __forceinline__ int gate_row0(int tid) {
    int l = tid & 63;
    int u = ((tid >> 6) << 5) + (l & 31);
    return (l < 32) ? u : 128 + u;
}

// ---------------------------------------------------------------------------
// K1: byte-decompose + embedding gather + encoder MLP (both pc and addr)
// ---------------------------------------------------------------------------
__global__ __launch_bounds__(256) void k_embed(
    const int* __restrict__ inp, const float* __restrict__ pc_emb,
    const float* __restrict__ ad_emb, const float* __restrict__ encW,
    const float* __restrict__ encB, float* __restrict__ emb)
{
    int idx = blockIdx.x * 256 + threadIdx.x;   // 512 blocks * 256 = B*S exactly
    int b = idx >> 11, t = idx & 2047;
    size_t base = (size_t)b * SS + t;
    int2 pa = ((const int2*)inp)[base];
    float* outp = emb + base * INS;

    float in[128];
    #pragma unroll
    for (int st = 0; st < 2; st++) {
        int v = (st == 0) ? pa.x : pa.y;
        const float* tbl = (st == 0) ? pc_emb : ad_emb;
        #pragma unroll
        for (int i = 0; i < 4; i++) {
            int by = (v >> (24 - 8 * i)) & 255;
            const float4* row = (const float4*)(tbl + ((size_t)i * 256 + by) * EMBS);
            #pragma unroll
            for (int k = 0; k < 8; k++) {
                float4 f = row[k];
                in[i * 32 + k * 4 + 0] = f.x;
                in[i * 32 + k * 4 + 1] = f.y;
                in[i * 32 + k * 4 + 2] = f.z;
                in[i * 32 + k * 4 + 3] = f.w;
            }
        }
        for (int e = 0; e < EMBS; e++) {        // e uniform -> encW via s_load
            const float* w = encW + e * 128;
            float acc = encB[e];
            #pragma unroll
            for (int k = 0; k < 128; k++) acc += in[k] * w[k];
            outp[st * EMBS + e] = sigm(acc);
        }
    }
}

// ---------------------------------------------------------------------------
// K2: dist[b][j] = mean over t of emb[b][t][j]
// ---------------------------------------------------------------------------
__global__ __launch_bounds__(256) void k_dist(const float* __restrict__ emb,
                                              float* __restrict__ dist)
{
    int b = blockIdx.x;
    int j = threadIdx.x & 63;
    int grp = threadIdx.x >> 6;
    float s = 0.f;
    for (int t = grp; t < SS; t += 4) s += emb[((size_t)b * SS + t) * INS + j];
    __shared__ float red[4][64];
    red[grp][j] = s;
    __syncthreads();
    if (grp == 0)
        dist[b * 64 + j] = (red[0][j] + red[1][j] + red[2][j] + red[3][j]) * (1.f / SS);
}

// ---------------------------------------------------------------------------
// K_XW: xw[b][t][tid] = f16pack( W_ih.g0 . x + b_ih.g0 + b_hh.g0 ,  same for g1 )
// one block = 128 consecutive rows; weights held in VGPRs as f16 pairs.
// ---------------------------------------------------------------------------
#define XW_TCHUNK 128
__global__ __launch_bounds__(256) void k_xw(
    const float* __restrict__ emb, const float* __restrict__ Wih,
    const float* __restrict__ bih, const float* __restrict__ bhh,
    half2v* __restrict__ xw)
{
    size_t r0 = (size_t)blockIdx.x * XW_TCHUNK;
    int tid = threadIdx.x;
    int g0 = gate_row0(tid), g1 = g0 + 256;

    half2v w0[32], w1[32];
    const float* w0p = Wih + (size_t)g0 * INS;
    const float* w1p = Wih + (size_t)g1 * INS;
    #pragma unroll
    for (int i = 0; i < 32; i++) {
        w0[i] = pack2(w0p[2 * i], w0p[2 * i + 1]);
        w1[i] = pack2(w1p[2 * i], w1p[2 * i + 1]);
    }
    float b0 = bih[g0] + bhh[g0], b1 = bih[g1] + bhh[g1];

    __shared__ alignas(16) half2v xsh[32];
    for (int r = 0; r < XW_TCHUNK; r++) {
        size_t row = r0 + r;
        if (tid < 32) {
            float2 xv = ((const float2*)(emb + row * INS))[tid];
            xsh[tid] = pack2(xv.x, xv.y);
        }
        __syncthreads();
        float a0a = 0.f, a0b = 0.f, a1a = 0.f, a1b = 0.f;
        #pragma unroll
        for (int i = 0; i < 32; i += 2) {
            half2v x0 = xsh[i], x1 = xsh[i + 1];
            a0a = fdot2f(x0, w0[i], a0a);
            a0b = fdot2f(x1, w0[i + 1], a0b);
            a1a = fdot2f(x0, w1[i], a1a);
            a1b = fdot2f(x1, w1[i + 1], a1b);
        }
        xw[row * 256 + tid] = pack2(b0 + a0a + a0b, b1 + a1a + a1b);
        __syncthreads();
    }
}

// ---------------------------------------------------------------------------
// K3 (fast): LSTM with precomputed xW. One block per batch element.
// 1 barrier/step: in-wave gate exchange via shfl_xor(32), double-buffered h.
// ---------------------------------------------------------------------------
__global__ __launch_bounds__(256, 1) void k_lstm2(
    const half2v* __restrict__ xw, const float* __restrict__ h0,
    const float* __restrict__ c0, const float* __restrict__ Whh,
    float* __restrict__ hfin)
{
    int b = blockIdx.x;
    int tid = threadIdx.x;
    int l = tid & 63;
    int u = ((tid >> 6) << 5) + (l & 31);
    bool lo = (l < 32);
    int g0 = lo ? u : 128 + u;
    int g1 = g0 + 256;

    // W_hh rows for my two gates, packed f16 in VGPRs
    half2v wh0[64], wh1[64];
    const float* h0p = Whh + (size_t)g0 * HS;
    const float* h1p = Whh + (size_t)g1 * HS;
    #pragma unroll
    for (int i = 0; i < 64; i++) {
        wh0[i] = pack2(h0p[2 * i], h0p[2 * i + 1]);
        wh1[i] = pack2(h1p[2 * i], h1p[2 * i + 1]);
    }

    __shared__ alignas(16) half2v hsh[2][64];   // double-buffered h (f16 pairs)
    float c = 0.f, h = 0.f;
    if (lo) c = c0[b * HS + u];
    if (tid < 128) ((_Float16*)hsh[0])[tid] = (_Float16)h0[b * HS + tid];
    __syncthreads();

    const half2v* xwrow = xw + (size_t)b * SS * 256 + tid;
    half2v xwa = xwrow[0];
    half2v xwb = xwrow[256];
    int p = 0;

    for (int t = 0; t < SS; t++) {
        half2v xwn = xwa;
        if (t + 2 < SS) xwn = xwrow[(size_t)(t + 2) * 256];   // prefetch, 2 ahead

        const half2v* hr = hsh[p];
        float a0a = 0.f, a0b = 0.f, a1a = 0.f, a1b = 0.f;
        #pragma unroll
        for (int i = 0; i < 64; i += 2) {
            half2v hh0 = hr[i], hh1 = hr[i + 1];
            a0a = fdot2f(hh0, wh0[i], a0a);
            a0b = fdot2f(hh1, wh0[i + 1], a0b);
            a1a = fdot2f(hh0, wh1[i], a1a);
            a1b = fdot2f(hh1, wh1[i + 1], a1b);
        }
        float a0 = (float)xwa.x + a0a + a0b;
        float a1 = (float)xwa.y + a1a + a1b;

        // lo: a0=i (sigm), a1=g (tanh) | hi: a0=f (sigm), a1=o (sigm)
        float act0 = sigm(a0);
        float act1 = lo ? ftanh(a1) : sigm(a1);
        float pf = __shfl_xor(act0, 32, 64);   // partner's f (for lo lanes)
        float po = __shfl_xor(act1, 32, 64);   // partner's o (for lo lanes)

        if (lo) {
            c = pf * c + act0 * act1;
            h = po * ftanh(c);
            ((_Float16*)hsh[p ^ 1])[u] = (_Float16)h;
        }
        __syncthreads();
        p ^= 1;
        xwa = xwb;
        xwb = xwn;
    }
    if (lo) hfin[b * HS + u] = h;
}

// ---------------------------------------------------------------------------
// K3 (fallback, ws too small for xW): round-1 structure, fast activations
// ---------------------------------------------------------------------------
__global__ __launch_bounds__(256, 1) void k_lstm_fb(
    const float* __restrict__ emb, const float* __restrict__ h0,
    const float* __restrict__ c0, const float* __restrict__ Wih,
    const float* __restrict__ Whh, const float* __restrict__ bih,
    const float* __restrict__ bhh, float* __restrict__ hfin)
{
    int b = blockIdx.x;
    int tid = threadIdx.x;

    half2v wih[2][32], whh[2][64];
    #pragma unroll
    for (int g = 0; g < 2; g++) {
        int gg = tid + g * 256;
        const float* wr = Wih + (size_t)gg * INS;
        #pragma unroll
        for (int i = 0; i < 32; i++) wih[g][i] = pack2(wr[2 * i], wr[2 * i + 1]);
        const float* hr = Whh + (size_t)gg * HS;
        #pragma unroll
        for (int i = 0; i < 64; i++) whh[g][i] = pack2(hr[2 * i], hr[2 * i + 1]);
    }
    float bias0 = bih[tid] + bhh[tid];
    float bias1 = bih[tid + 256] + bhh[tid + 256];

    __shared__ alignas(16) half2v xh[96];
    __shared__ float f_act[128], o_act[128];
    __shared__ float xf[64], hf[128];

    float c = 0.f, h = 0.f;
    if (tid < 128) c = c0[b * HS + tid];

    const float* xrow = emb + (size_t)b * SS * INS;
    if (tid < 64) xf[tid] = xrow[tid];
    if (tid < 128) hf[tid] = h0[b * HS + tid];
    __syncthreads();
    if (tid < 32) xh[tid] = pack2(xf[2 * tid], xf[2 * tid + 1]);
    else if (tid < 96) { int uu = tid - 32; xh[tid] = pack2(hf[2 * uu], hf[2 * uu + 1]); }
    __syncthreads();

    for (int t = 0; t < SS; t++) {
        float xn = 0.f;
        if (tid >= 128 && tid < 192 && t + 1 < SS) xn = xrow[(size_t)(t + 1) * INS + (tid - 128)];

        float a0a = 0.f, a0b = 0.f, a1a = 0.f, a1b = 0.f;
        #pragma unroll
        for (int i = 0; i < 32; i += 2) {
            half2v x0 = xh[i], x1 = xh[i + 1];
            a0a = fdot2f(x0, wih[0][i], a0a);
            a0b = fdot2f(x1, wih[0][i + 1], a0b);
            a1a = fdot2f(x0, wih[1][i], a1a);
            a1b = fdot2f(x1, wih[1][i + 1], a1b);
        }
        #pragma unroll
        for (int i = 0; i < 64; i += 2) {
            half2v h0v = xh[32 + i], h1v = xh[32 + i + 1];
            a0a = fdot2f(h0v, whh[0][i], a0a);
            a0b = fdot2f(h1v, whh[0][i + 1], a0b);
            a1a = fdot2f(h0v, whh[1][i], a1a);
            a1b = fdot2f(h1v, whh[1][i + 1], a1b);
        }
        float a0 = bias0 + a0a + a0b;
        float a1 = bias1 + a1a + a1b;

        float iact = 0.f, gact = 0.f;
        if (tid < 128) { iact = sigm(a0); gact = ftanh(a1); }
        else           { f_act[tid - 128] = sigm(a0); o_act[tid - 128] = sigm(a1); }
        __syncthreads();

        if (tid < 128) {
            c = f_act[tid] * c + iact * gact;
            h = o_act[tid] * ftanh(c);
            hf[tid] = h;
        } else if (tid < 192) {
            xf[tid - 128] = xn;
        }
        __syncthreads();

        if (tid < 32) xh[tid] = pack2(xf[2 * tid], xf[2 * tid + 1]);
        else if (tid < 96) { int uu = tid - 32; xh[tid] = pack2(hf[2 * uu], hf[2 * uu + 1]); }
        __syncthreads();
    }
    if (tid < 128) hfin[b * HS + tid] = h;
}

// ---------------------------------------------------------------------------
// K4: decoder logits + T=1e-3 softmax + freq-rec head. one block per b.
// ---------------------------------------------------------------------------
__global__ __launch_bounds__(256) void k_head(
    const float* __restrict__ hfin, const float* __restrict__ decW,
    const float* __restrict__ decB, const float* __restrict__ ad_emb,
    const float* __restrict__ encW, const float* __restrict__ encB,
    const float* __restrict__ dist, const float* __restrict__ fc1W,
    const float* __restrict__ fc1b, const float* __restrict__ fc2W,
    const float* __restrict__ fc2b, float* __restrict__ outp)
{
    int b = blockIdx.x;
    int tid = threadIdx.x;
    __shared__ float hsh[128];
    __shared__ float logit_s[4][256];
    __shared__ float probs_s[4][256];
    __shared__ float be_s[128];
    __shared__ float fe_dist[96];
    __shared__ float fr1[10];

    if (tid < 128) hsh[tid] = hfin[b * HS + tid];
    __syncthreads();

    #pragma unroll
    for (int k = 0; k < 4; k++) {
        const float* w = decW + ((size_t)k * OUTS + tid) * HS;
        float acc = decB[k * OUTS + tid];
        #pragma unroll 8
        for (int hh = 0; hh < HS; hh++) acc += hsh[hh] * w[hh];
        logit_s[k][tid] = acc;
        outp[65536 + k * 16384 + b * 256 + tid] = acc;   // logits output
    }
    __syncthreads();

    {
        int k = tid >> 6, lane = tid & 63;
        float v0 = logit_s[k][lane],       v1 = logit_s[k][lane + 64];
        float v2 = logit_s[k][lane + 128], v3 = logit_s[k][lane + 192];
        float m = fmaxf(fmaxf(v0, v1), fmaxf(v2, v3));
        for (int off = 32; off; off >>= 1) m = fmaxf(m, __shfl_xor(m, off, 64));
        float e0 = fexp2((v0 - m) * 1442.695041f), e1 = fexp2((v1 - m) * 1442.695041f);
        float e2 = fexp2((v2 - m) * 1442.695041f), e3 = fexp2((v3 - m) * 1442.695041f);
        float s = e0 + e1 + e2 + e3;
        for (int off = 32; off; off >>= 1) s += __shfl_xor(s, off, 64);
        float inv = 1.f / s;
        float p0 = e0 * inv, p1 = e1 * inv, p2 = e2 * inv, p3 = e3 * inv;
        probs_s[k][lane] = p0;        probs_s[k][lane + 64] = p1;
        probs_s[k][lane + 128] = p2;  probs_s[k][lane + 192] = p3;
        outp[k * 16384 + b * 256 + lane] = p0;
        outp[k * 16384 + b * 256 + lane + 64] = p1;
        outp[k * 16384 + b * 256 + lane + 128] = p2;
        outp[k * 16384 + b * 256 + lane + 192] = p3;
    }
    __syncthreads();

    if (tid < 128) {
        int k = tid >> 5, e = tid & 31;
        const float* te = ad_emb + (size_t)k * OUTS * EMBS + e;
        float acc = 0.f;
        #pragma unroll 8
        for (int o = 0; o < OUTS; o++) acc += probs_s[k][o] * te[o * EMBS];
        be_s[tid] = acc;
    }
    __syncthreads();

    if (tid < 32) {
        const float* w = encW + tid * 128;
        float acc = encB[tid];
        #pragma unroll 8
        for (int kk = 0; kk < 128; kk++) acc += be_s[kk] * w[kk];
        fe_dist[tid] = sigm(acc);
    } else if (tid < 96) {
        fe_dist[tid] = dist[b * 64 + (tid - 32)];
    }
    __syncthreads();

    if (tid < 10) {
        float acc = fc1b[tid];
        for (int kk = 0; kk < 96; kk++) acc += fe_dist[kk] * fc1W[tid * 96 + kk];
        fr1[tid] = fmaxf(acc, 0.f);
    }
    __syncthreads();

    if (tid < 2) {
        float acc = fc2b[tid];
        for (int kk = 0; kk < 10; kk++) acc += fr1[kk] * fc2W[tid * 10 + kk];
        outp[131072 + tid * 64 + b] = sigm(acc);
    }
}

// ---------------------------------------------------------------------------
extern "C" void kernel_launch(void* const* d_in, const int* in_sizes, int n_in,
                              void* d_out, int out_size, void* d_ws, size_t ws_size,
                              hipStream_t stream)
{
    const int*   inp    = (const int*)d_in[0];
    const float* h0     = (const float*)d_in[1];
    const float* c0     = (const float*)d_in[2];
    const float* pc_emb = (const float*)d_in[3];
    const float* ad_emb = (const float*)d_in[4];
    const float* encW   = (const float*)d_in[5];
    const float* encB   = (const float*)d_in[6];
    const float* Wih    = (const float*)d_in[7];
    const float* Whh    = (const float*)d_in[8];
    const float* bih    = (const float*)d_in[9];
    const float* bhh    = (const float*)d_in[10];
    const float* decW   = (const float*)d_in[11];
    const float* decB   = (const float*)d_in[12];
    const float* fc1W   = (const float*)d_in[13];
    const float* fc1b   = (const float*)d_in[14];
    const float* fc2W   = (const float*)d_in[15];
    const float* fc2b   = (const float*)d_in[16];

    if (ws_size < WS_SMALL * 4ull) return;  // clean fail if ws too small

    float* ws   = (float*)d_ws;
    float* emb  = ws;
    float* dist = ws + WS_DIST;
    float* hfin = ws + WS_HFIN;
    float* outp = (float*)d_out;
    bool big = (ws_size >= WS_BIG * 4ull);

    hipLaunchKernelGGL(k_embed, dim3(512), dim3(256), 0, stream,
                       inp, pc_emb, ad_emb, encW, encB, emb);
    hipLaunchKernelGGL(k_dist, dim3(64), dim3(256), 0, stream, emb, dist);
    if (big) {
        half2v* xwp = (half2v*)(ws + WS_XW);
        hipLaunchKernelGGL(k_xw, dim3(BS * SS / XW_TCHUNK), dim3(256), 0, stream,
                           emb, Wih, bih, bhh, xwp);
        hipLaunchKernelGGL(k_lstm2, dim3(64), dim3(256), 0, stream,
                           xwp, h0, c0, Whh, hfin);
    } else {
        hipLaunchKernelGGL(k_lstm_fb, dim3(64), dim3(256), 0, stream,
                           emb, h0, c0, Wih, Whh, bih, bhh, hfin);
    }
    hipLaunchKernelGGL(k_head, dim3(64), dim3(256), 0, stream,
                       hfin, decW, decB, ad_emb, encW, encB, dist,
                       fc1W, fc1b, fc2W, fc2b, outp);
}